// Round 21
// baseline (89.939 us; speedup 1.0000x reference)
//
#include <hip/hip_runtime.h>
#include <hip/hip_bf16.h>

// DeConv2d = 32 per-channel MLPs (128->256->256->4) over 8192 px + 2x2 shuffle.
//
// R21: R20's profile showed VGPR=116 -> 4 waves/SIMD allowed; the occupancy
// limiter was the 88KB LDS (1 block/CU). R21 shrinks LDS to 48KB so 2 blocks
// co-reside (16 waves/CU): pix 2x8K @0 | h1 SINGLE 16K @16K | h2 SINGLE 16K
// @32K. Loop restructured (race-audited): per iter i,
//   A:{L2(i) h1->h2, stage(i+2)} bar; B:{L3(i) h2->out, L1(i+1) pix->h1} bar.
// Plain __syncthreads (counted-vmcnt gained ~0 in R14). 4-bit swizzle (R20:
// conflicts 8.9M->2.1M). R14's 2-deep frag scheme (lowest reg pressure).
//
// Workspace: pix [8192][128] bf16 @0; W1t [32][256][128] @2MB; W2t [32][256][256] @4MB;
//            W3t [32][16][256] @8MB (rows 4..15 zero).

#define IC    128
#define IHW   1024
#define OCH   32
#define HDIM  256

typedef float  f32x4  __attribute__((ext_vector_type(4)));
typedef float  f32x2  __attribute__((ext_vector_type(2)));
typedef __bf16 bf16x8 __attribute__((ext_vector_type(8)));
typedef unsigned short us8 __attribute__((ext_vector_type(8)));
typedef unsigned int u32;

static __device__ __forceinline__ unsigned short f2bf(float f) {
  __hip_bfloat16 h = __float2bfloat16(f);
  return __builtin_bit_cast(unsigned short, h);
}

static __device__ __forceinline__ u32 cvtpk(float lo, float hi) {
  u32 r;
  asm("v_cvt_pk_bf16_f32 %0, %1, %2" : "=v"(r) : "v"(lo), "v"(hi));
  return r;
}

static __device__ __forceinline__ bf16x8 ld16(const unsigned short* p) {
  return __builtin_bit_cast(bf16x8, *reinterpret_cast<const uint4*>(p));
}

static __device__ __forceinline__ void gl_lds16(const unsigned short* g, char* l) {
  __builtin_amdgcn_global_load_lds(
      (const __attribute__((address_space(1))) u32*)g,
      (__attribute__((address_space(3))) u32*)l,
      16, 0, 0);
}

// ---- fused prepass (R14-proven) ----
static __device__ void transpose_dev(const float* __restrict__ src,
                                     unsigned short* __restrict__ dst,
                                     int NR, int NC, int nrt, int nct,
                                     int bid, int t, float* tl)
{
  const int ct = bid % nct;
  const int rt = (bid / nct) % nrt;
  const int b  = bid / (nct * nrt);

  const float* sb = src + ((size_t)b * NR + (rt << 6)) * NC + (ct << 6);
  const int col = (t & 15) << 2;
  const int rq  = t >> 4;
#pragma unroll
  for (int rr = 0; rr < 4; ++rr) {
    int row = (rr << 4) + rq;
    f32x4 v = *reinterpret_cast<const f32x4*>(sb + row * NC + col);
#pragma unroll
    for (int i = 0; i < 4; ++i) tl[row * 65 + col + i] = v[i];
  }
  __syncthreads();

  unsigned short* db = dst + ((size_t)b * NC + (ct << 6)) * NR + (rt << 6);
  const int r0 = (t & 7) << 3;
  const int cq = t >> 3;
#pragma unroll
  for (int cr = 0; cr < 2; ++cr) {
    int c = (cr << 5) + cq;
    us8 vv;
#pragma unroll
    for (int i = 0; i < 8; ++i) vv[i] = f2bf(tl[(r0 + i) * 65 + c]);
    *reinterpret_cast<us8*>(db + (size_t)c * NR + r0) = vv;
  }
}

__global__ __launch_bounds__(256) void prepass_k(
    const float* __restrict__ x,  unsigned short* __restrict__ pix,
    const float* __restrict__ W1, unsigned short* __restrict__ W1t,
    const float* __restrict__ W2, unsigned short* __restrict__ W2t,
    const float* __restrict__ W3, unsigned short* __restrict__ W3t)
{
  __shared__ float tl[64 * 65];
  const int bid = blockIdx.x;
  const int t   = threadIdx.x;
  if (bid < 256) {
    transpose_dev(x, pix, 128, 1024, 2, 16, bid, t, tl);
  } else if (bid < 512) {
    transpose_dev(W1, W1t, 128, 256, 2, 4, bid - 256, t, tl);
  } else if (bid < 1024) {
    transpose_dev(W2, W2t, 256, 256, 4, 4, bid - 512, t, tl);
  } else {
    int idx = ((bid - 1024) << 8) + t;
    int k = idx & 255, nn = (idx >> 8) & 15, o = idx >> 12;
    W3t[idx] = (nn < 4) ? f2bf(W3[(o * HDIM + k) * 4 + nn]) : (unsigned short)0;
  }
}

// ---- fused 3-layer MLP, 2-phase, single h1/h2, 2 blocks/CU ----
// Block = 512 thr = 8 waves, (group o, 256 px = 8 tiles of 32). Wave w owns
// n-rows [w*32,w*32+32) (nf=2). D frag: col=lane&15 -> px, row=(lane>>4)*4+reg -> n.
// LDS 48KB: pix 2x8K @0, h1 16K @16384, h2 16K @32768. Swizzle ^((m&15)<<4).

#define LDB(dst, buf, ROW, ks)                                                   \
  _Pragma("unroll")                                                              \
  for (int mf = 0; mf < 2; ++mf) {                                               \
    int m = (mf << 4) + l15;                                                     \
    dst[mf] = *reinterpret_cast<const bf16x8*>(                                  \
        (buf) + ((((m << (ROW)) + ((ks) << 6) + (kgrp << 1))) ^ ((l15 & 15) << 4)));\
  }

#define MF4(WR, KS, BP)                                                          \
  __builtin_amdgcn_s_setprio(1);                                                 \
  _Pragma("unroll")                                                              \
  for (int nf = 0; nf < 2; ++nf)                                                 \
    _Pragma("unroll")                                                            \
    for (int mf = 0; mf < 2; ++mf)                                               \
      acc[nf][mf] = __builtin_amdgcn_mfma_f32_16x16x32_bf16(WR[nf][KS], BP[mf], acc[nf][mf], 0, 0, 0); \
  __builtin_amdgcn_s_setprio(0);

#define EPI(dst)                                                                 \
  _Pragma("unroll")                                                              \
  for (int nf = 0; nf < 2; ++nf) {                                               \
    int n0 = wnb + (nf << 4) + (lg << 2);                                        \
    _Pragma("unroll")                                                            \
    for (int mf = 0; mf < 2; ++mf) {                                             \
      int m = (mf << 4) + l15;                                                   \
      uint2 hv;                                                                  \
      hv.x = cvtpk(fmaxf(acc[nf][mf][0], 0.f), fmaxf(acc[nf][mf][1], 0.f));      \
      hv.y = cvtpk(fmaxf(acc[nf][mf][2], 0.f), fmaxf(acc[nf][mf][3], 0.f));      \
      *reinterpret_cast<uint2*>(                                                 \
          (dst) + (((m << 9) + (n0 << 1)) ^ ((l15 & 15) << 4))) = hv;            \
    }                                                                            \
  }

#define INIT_ACC(BB)                                                             \
  _Pragma("unroll")                                                              \
  for (int nf = 0; nf < 2; ++nf)                                                 \
    _Pragma("unroll")                                                            \
    for (int mf = 0; mf < 2; ++mf) acc[nf][mf] = BB[nf];

// stage one 32-px tile (8KB): 512 threads x 16B; pre-swizzled source (4-bit)
#define STAGE(PXB, BUF)                                                          \
  {                                                                              \
    int m = t >> 4, c16 = t & 15;                                                \
    gl_lds16(pix + (size_t)((PXB) + m) * IC + ((c16 ^ (m & 15)) << 3),           \
             (BUF) + t * 16);                                                    \
  }

__global__ __launch_bounds__(512, 2) void fused_mlp_k(
    const unsigned short* __restrict__ pix,
    const unsigned short* __restrict__ W1t,
    const unsigned short* __restrict__ W2t,
    const unsigned short* __restrict__ W3t,
    const float* __restrict__ b1,
    const float* __restrict__ b2,
    const float* __restrict__ b3f,
    float* __restrict__ out)
{
  __shared__ __align__(16) char lds[49152];
  const int t    = threadIdx.x;
  const int lane = t & 63;
  const int w    = t >> 6;                          // 0..7
  const int bx   = blockIdx.x;
  const int o    = ((bx & 7) << 2) | ((bx >> 3) & 3);   // 4 groups per XCD
  const int pixbase = (bx >> 5) << 8;               // 256 px per block (8 tiles)

  const int l15  = lane & 15;
  const int lg   = lane >> 4;
  const int kgrp = lg << 3;
  const int wnb  = w << 5;

  char* pixb[2] = { lds, lds + 8192 };
  char* h1v     = lds + 16384;                      // SINGLE buffer
  char* h2v     = lds + 32768;                      // SINGLE buffer

  // ---- prologue: stage tiles 0,1; resident weights; biases ----
  STAGE(pixbase,      pixb[0])
  STAGE(pixbase + 32, pixb[1])

  const unsigned short* W1p = W1t + (o << 15) + (wnb + l15) * IC + kgrp;
  const unsigned short* W2p = W2t + (o << 16) + (wnb + l15) * HDIM + kgrp;
  bf16x8 W1r[2][4], W2r[2][8], W3r[8];
#pragma unroll
  for (int nf = 0; nf < 2; ++nf)
#pragma unroll
    for (int ks = 0; ks < 4; ++ks)
      W1r[nf][ks] = ld16(W1p + (nf << 4) * IC + (ks << 5));
#pragma unroll
  for (int nf = 0; nf < 2; ++nf)
#pragma unroll
    for (int ks = 0; ks < 8; ++ks)
      W2r[nf][ks] = ld16(W2p + (nf << 4) * HDIM + (ks << 5));
#pragma unroll
  for (int ks = 0; ks < 8; ++ks)    // L3 A-frag: row n=l15, k=ks*32+lg*8
    W3r[ks] = ld16(W3t + (o << 12) + l15 * HDIM + (ks << 5) + kgrp);

  f32x4 bb1[2], bb2[2];
#pragma unroll
  for (int nf = 0; nf < 2; ++nf) {
    bb1[nf] = *reinterpret_cast<const f32x4*>(b1 + (o << 8) + wnb + (nf << 4) + (lg << 2));
    bb2[nf] = *reinterpret_cast<const f32x4*>(b2 + (o << 8) + wnb + (nf << 4) + (lg << 2));
  }
  const f32x4 b3v = *reinterpret_cast<const f32x4*>(b3f + (o << 2));

  f32x4 acc[2][2];
  bf16x8 bp[2], bq[2];

  __syncthreads();   // tiles 0,1 staged (full drain)

  // L1(0): pixb[0] -> h1
  INIT_ACC(bb1)
  LDB(bp, pixb[0], 8, 0)
  LDB(bq, pixb[0], 8, 1) MF4(W1r, 0, bp)
  LDB(bp, pixb[0], 8, 2) MF4(W1r, 1, bq)
  LDB(bq, pixb[0], 8, 3) MF4(W1r, 2, bp)
                         MF4(W1r, 3, bq)
  EPI(h1v)
  __syncthreads();   // h1(0) visible

  // ---- main loop: iter i = A{L2(i)->h2, stage(i+2)} bar
  //                          B{L3(i) h2->out, L1(i+1)->h1} bar ----
#pragma unroll
  for (int i = 0; i <= 7; ++i) {
    // ===== Phase A: L2(i): h1 -> h2 =====
    INIT_ACC(bb2)
    LDB(bp, h1v, 9, 0)
    LDB(bq, h1v, 9, 1) MF4(W2r, 0, bp)
    LDB(bp, h1v, 9, 2) MF4(W2r, 1, bq)
    LDB(bq, h1v, 9, 3) MF4(W2r, 2, bp)
    LDB(bp, h1v, 9, 4) MF4(W2r, 3, bq)
    LDB(bq, h1v, 9, 5) MF4(W2r, 4, bp)
    LDB(bp, h1v, 9, 6) MF4(W2r, 5, bq)
    LDB(bq, h1v, 9, 7) MF4(W2r, 6, bp)
                       MF4(W2r, 7, bq)
    EPI(h2v)
    if (i <= 5) STAGE(pixbase + ((i + 2) << 5), pixb[i & 1])

    __syncthreads();   // h2(i) visible; h1 reads done; stage drained

    // ===== Phase B: L3(i): h2 -> out (waves 0,1) =====
    if (w < 2) {
      const int m3 = (w << 4) + l15;
      f32x4 a3a = b3v;
      f32x4 a3b = {0.f, 0.f, 0.f, 0.f};
#pragma unroll
      for (int ks = 0; ks < 8; ks += 2) {
        bf16x8 bh0 = *reinterpret_cast<const bf16x8*>(
            h2v + (((m3 << 9) + (ks << 6) + (kgrp << 1)) ^ ((l15 & 15) << 4)));
        bf16x8 bh1 = *reinterpret_cast<const bf16x8*>(
            h2v + (((m3 << 9) + ((ks + 1) << 6) + (kgrp << 1)) ^ ((l15 & 15) << 4)));
        a3a = __builtin_amdgcn_mfma_f32_16x16x32_bf16(W3r[ks],     bh0, a3a, 0, 0, 0);
        a3b = __builtin_amdgcn_mfma_f32_16x16x32_bf16(W3r[ks + 1], bh1, a3b, 0, 0, 0);
      }
      if (lane < 16) {
        int pixel = pixbase + (i << 5) + m3;
        int n = pixel >> 10, p = pixel & 1023;
        int ii = p >> 5, jj = p & 31;
        float* ob = out + ((size_t)((n << 5) + o) << 12) + (ii << 7) + (jj << 1);
        f32x2 r0 = { a3a[0] + a3b[0], a3a[1] + a3b[1] };
        f32x2 r1 = { a3a[2] + a3b[2], a3a[3] + a3b[3] };
        *reinterpret_cast<f32x2*>(ob) = r0;
        *reinterpret_cast<f32x2*>(ob + 64) = r1;
      }
    }

    // ===== Phase B: L1(i+1): pixb[(i+1)&1] -> h1 =====
    if (i <= 6) {
      char* psrc = pixb[(i + 1) & 1];
      INIT_ACC(bb1)
      LDB(bp, psrc, 8, 0)
      LDB(bq, psrc, 8, 1) MF4(W1r, 0, bp)
      LDB(bp, psrc, 8, 2) MF4(W1r, 1, bq)
      LDB(bq, psrc, 8, 3) MF4(W1r, 2, bp)
                          MF4(W1r, 3, bq)
      EPI(h1v)
    }

    if (i < 7) __syncthreads();   // h1(i+1) visible; h2 reads done
  }
}

extern "C" void kernel_launch(void* const* d_in, const int* in_sizes, int n_in,
                              void* d_out, int out_size, void* d_ws, size_t ws_size,
                              hipStream_t stream) {
  const float* x  = (const float*)d_in[0];
  const float* W1 = (const float*)d_in[1];
  const float* b1 = (const float*)d_in[2];
  const float* W2 = (const float*)d_in[3];
  const float* b2 = (const float*)d_in[4];
  const float* W3 = (const float*)d_in[5];
  const float* b3 = (const float*)d_in[6];
  float* out = (float*)d_out;

  char* ws = (char*)d_ws;
  unsigned short* pixw = (unsigned short*)(ws);
  unsigned short* W1t  = (unsigned short*)(ws + (size_t)(2u << 20));
  unsigned short* W2t  = (unsigned short*)(ws + (size_t)(4u << 20));
  unsigned short* W3t  = (unsigned short*)(ws + (size_t)(8u << 20));

  prepass_k<<<1536, 256, 0, stream>>>(x, pixw, W1, W1t, W2, W2t, W3, W3t);
  fused_mlp_k<<<1024, 512, 0, stream>>>(pixw, W1t, W2t, W3t, b1, b2, b3, out);
}

// Round 22
// 83.914 us; speedup vs baseline: 1.0718x; 1.0718x over previous
//
#include <hip/hip_runtime.h>
#include <hip/hip_bf16.h>

// DeConv2d = 32 per-channel MLPs (128->256->256->4) over 8192 px + 2x2 shuffle.
//
// FINAL (R22 = R20 verbatim, the session's best verified kernel: 84.1us).
// R21's occupancy theory failed (48KB LDS did NOT yield 2 blocks/CU; limiter
// is not LDS) and its 2-barrier restructure cost 7% -> restored R20.
// Ladder: 151 -> 84.1us via: bf16 MFMA + weight/pixel transpose prepass (R1),
// cross-layer single-barrier software pipeline (R10, 86us), prologue-resident
// weights, counted-vmcnt stage float + fused prepass (R14), 4-bit LDS XOR
// swizzle (R20: bank conflicts 8.9M->2.1M, 84.1us).
// Remaining gap to the ~26us MFMA floor is nf=2 LDS-read amplification; every
// structure attacking it (4-wave nf=4, interleave, 16-tile) crashed (5x).
//
// Workspace: pix [8192][128] bf16 @0; W1t [32][256][128] @2MB; W2t [32][256][256] @4MB;
//            W3t [32][16][256] @8MB (rows 4..15 zero).

#define IC    128
#define IHW   1024
#define OCH   32
#define HDIM  256

typedef float  f32x4  __attribute__((ext_vector_type(4)));
typedef float  f32x2  __attribute__((ext_vector_type(2)));
typedef __bf16 bf16x8 __attribute__((ext_vector_type(8)));
typedef unsigned short us8 __attribute__((ext_vector_type(8)));
typedef unsigned int u32;

static __device__ __forceinline__ unsigned short f2bf(float f) {
  __hip_bfloat16 h = __float2bfloat16(f);
  return __builtin_bit_cast(unsigned short, h);
}

static __device__ __forceinline__ u32 cvtpk(float lo, float hi) {
  u32 r;
  asm("v_cvt_pk_bf16_f32 %0, %1, %2" : "=v"(r) : "v"(lo), "v"(hi));
  return r;
}

static __device__ __forceinline__ bf16x8 ld16(const unsigned short* p) {
  return __builtin_bit_cast(bf16x8, *reinterpret_cast<const uint4*>(p));
}

static __device__ __forceinline__ void gl_lds16(const unsigned short* g, char* l) {
  __builtin_amdgcn_global_load_lds(
      (const __attribute__((address_space(1))) u32*)g,
      (__attribute__((address_space(3))) u32*)l,
      16, 0, 0);
}

// ---- fused prepass ----
static __device__ void transpose_dev(const float* __restrict__ src,
                                     unsigned short* __restrict__ dst,
                                     int NR, int NC, int nrt, int nct,
                                     int bid, int t, float* tl)
{
  const int ct = bid % nct;
  const int rt = (bid / nct) % nrt;
  const int b  = bid / (nct * nrt);

  const float* sb = src + ((size_t)b * NR + (rt << 6)) * NC + (ct << 6);
  const int col = (t & 15) << 2;
  const int rq  = t >> 4;
#pragma unroll
  for (int rr = 0; rr < 4; ++rr) {
    int row = (rr << 4) + rq;
    f32x4 v = *reinterpret_cast<const f32x4*>(sb + row * NC + col);
#pragma unroll
    for (int i = 0; i < 4; ++i) tl[row * 65 + col + i] = v[i];
  }
  __syncthreads();

  unsigned short* db = dst + ((size_t)b * NC + (ct << 6)) * NR + (rt << 6);
  const int r0 = (t & 7) << 3;
  const int cq = t >> 3;
#pragma unroll
  for (int cr = 0; cr < 2; ++cr) {
    int c = (cr << 5) + cq;
    us8 vv;
#pragma unroll
    for (int i = 0; i < 8; ++i) vv[i] = f2bf(tl[(r0 + i) * 65 + c]);
    *reinterpret_cast<us8*>(db + (size_t)c * NR + r0) = vv;
  }
}

__global__ __launch_bounds__(256) void prepass_k(
    const float* __restrict__ x,  unsigned short* __restrict__ pix,
    const float* __restrict__ W1, unsigned short* __restrict__ W1t,
    const float* __restrict__ W2, unsigned short* __restrict__ W2t,
    const float* __restrict__ W3, unsigned short* __restrict__ W3t)
{
  __shared__ float tl[64 * 65];
  const int bid = blockIdx.x;
  const int t   = threadIdx.x;
  if (bid < 256) {
    transpose_dev(x, pix, 128, 1024, 2, 16, bid, t, tl);
  } else if (bid < 512) {
    transpose_dev(W1, W1t, 128, 256, 2, 4, bid - 256, t, tl);
  } else if (bid < 1024) {
    transpose_dev(W2, W2t, 256, 256, 4, 4, bid - 512, t, tl);
  } else {
    int idx = ((bid - 1024) << 8) + t;
    int k = idx & 255, nn = (idx >> 8) & 15, o = idx >> 12;
    W3t[idx] = (nn < 4) ? f2bf(W3[(o * HDIM + k) * 4 + nn]) : (unsigned short)0;
  }
}

// ---- fused 3-layer MLP, cross-layer pipelined, counted-vmcnt barrier ----
// Block = 512 thr = 8 waves, (group o, 256 px = 8 tiles of 32). Wave w owns
// n-rows [w*32,w*32+32) (nf=2). D frag: col=lane&15 -> px, row=(lane>>4)*4+reg -> n.
// LDS 88KB: pix 3x8K @0, h1 2x16K @24576, h2 2x16K @57344. Swizzle ^((m&15)<<4).

#define LDB(dst, buf, ROW, ks)                                                   \
  _Pragma("unroll")                                                              \
  for (int mf = 0; mf < 2; ++mf) {                                               \
    int m = (mf << 4) + l15;                                                     \
    dst[mf] = *reinterpret_cast<const bf16x8*>(                                  \
        (buf) + ((((m << (ROW)) + ((ks) << 6) + (kgrp << 1))) ^ ((l15 & 15) << 4)));\
  }

#define MF4(WR, KS, BP)                                                          \
  __builtin_amdgcn_s_setprio(1);                                                 \
  _Pragma("unroll")                                                              \
  for (int nf = 0; nf < 2; ++nf)                                                 \
    _Pragma("unroll")                                                            \
    for (int mf = 0; mf < 2; ++mf)                                               \
      acc[nf][mf] = __builtin_amdgcn_mfma_f32_16x16x32_bf16(WR[nf][KS], BP[mf], acc[nf][mf], 0, 0, 0); \
  __builtin_amdgcn_s_setprio(0);

#define EPI(dst)                                                                 \
  _Pragma("unroll")                                                              \
  for (int nf = 0; nf < 2; ++nf) {                                               \
    int n0 = wnb + (nf << 4) + (lg << 2);                                        \
    _Pragma("unroll")                                                            \
    for (int mf = 0; mf < 2; ++mf) {                                             \
      int m = (mf << 4) + l15;                                                   \
      uint2 hv;                                                                  \
      hv.x = cvtpk(fmaxf(acc[nf][mf][0], 0.f), fmaxf(acc[nf][mf][1], 0.f));      \
      hv.y = cvtpk(fmaxf(acc[nf][mf][2], 0.f), fmaxf(acc[nf][mf][3], 0.f));      \
      *reinterpret_cast<uint2*>(                                                 \
          (dst) + (((m << 9) + (n0 << 1)) ^ ((l15 & 15) << 4))) = hv;            \
    }                                                                            \
  }

#define INIT_ACC(BB)                                                             \
  _Pragma("unroll")                                                              \
  for (int nf = 0; nf < 2; ++nf)                                                 \
    _Pragma("unroll")                                                            \
    for (int mf = 0; mf < 2; ++mf) acc[nf][mf] = BB[nf];

// stage one 32-px tile (8KB): 512 threads x 16B; pre-swizzled source (4-bit)
#define STAGE(PXB, BUF)                                                          \
  {                                                                              \
    int m = t >> 4, c16 = t & 15;                                                \
    gl_lds16(pix + (size_t)((PXB) + m) * IC + ((c16 ^ (m & 15)) << 3),           \
             (BUF) + t * 16);                                                    \
  }

// counted-vmcnt pipeline barrier (rule-#18 fences)
#define PIPE_BARRIER(N)                                                          \
  asm volatile("s_waitcnt vmcnt(" #N ") lgkmcnt(0)" ::: "memory");               \
  __builtin_amdgcn_sched_barrier(0);                                             \
  __builtin_amdgcn_s_barrier();                                                  \
  __builtin_amdgcn_sched_barrier(0);

__global__ __launch_bounds__(512, 2) void fused_mlp_k(
    const unsigned short* __restrict__ pix,
    const unsigned short* __restrict__ W1t,
    const unsigned short* __restrict__ W2t,
    const unsigned short* __restrict__ W3t,
    const float* __restrict__ b1,
    const float* __restrict__ b2,
    const float* __restrict__ b3f,
    float* __restrict__ out)
{
  __shared__ __align__(16) char lds[90112];
  const int t    = threadIdx.x;
  const int lane = t & 63;
  const int w    = t >> 6;                          // 0..7
  const int bx   = blockIdx.x;
  const int o    = ((bx & 7) << 2) | ((bx >> 3) & 3);   // 4 groups per XCD
  const int pixbase = (bx >> 5) << 8;               // 256 px per block (8 tiles)

  const int l15  = lane & 15;
  const int lg   = lane >> 4;
  const int kgrp = lg << 3;
  const int wnb  = w << 5;

  char* pixb[3] = { lds, lds + 8192, lds + 16384 };
  char* h1b[2]  = { lds + 24576, lds + 40960 };
  char* h2b[2]  = { lds + 57344, lds + 73728 };

  // ---- prologue: stage tiles 0,1,2; resident weights; biases ----
  STAGE(pixbase,      pixb[0])
  STAGE(pixbase + 32, pixb[1])
  STAGE(pixbase + 64, pixb[2])

  const unsigned short* W1p = W1t + (o << 15) + (wnb + l15) * IC + kgrp;
  const unsigned short* W2p = W2t + (o << 16) + (wnb + l15) * HDIM + kgrp;
  bf16x8 W1r[2][4], W2r[2][8], W3r[8];
#pragma unroll
  for (int nf = 0; nf < 2; ++nf)
#pragma unroll
    for (int ks = 0; ks < 4; ++ks)
      W1r[nf][ks] = ld16(W1p + (nf << 4) * IC + (ks << 5));
#pragma unroll
  for (int nf = 0; nf < 2; ++nf)
#pragma unroll
    for (int ks = 0; ks < 8; ++ks)
      W2r[nf][ks] = ld16(W2p + (nf << 4) * HDIM + (ks << 5));
#pragma unroll
  for (int ks = 0; ks < 8; ++ks)    // L3 A-frag: row n=l15, k=ks*32+lg*8
    W3r[ks] = ld16(W3t + (o << 12) + l15 * HDIM + (ks << 5) + kgrp);

  f32x4 bb1[2], bb2[2];
#pragma unroll
  for (int nf = 0; nf < 2; ++nf) {
    bb1[nf] = *reinterpret_cast<const f32x4*>(b1 + (o << 8) + wnb + (nf << 4) + (lg << 2));
    bb2[nf] = *reinterpret_cast<const f32x4*>(b2 + (o << 8) + wnb + (nf << 4) + (lg << 2));
  }
  const f32x4 b3v = *reinterpret_cast<const f32x4*>(b3f + (o << 2));

  f32x4 acc[2][2];
  bf16x8 bp[2], bq[2], br[2], bs[2];

  __syncthreads();   // P0: tiles 0-2 staged, full drain (one-time)

  // L1(0) -> h1b[0]: all 4 frag-pairs upfront
  INIT_ACC(bb1)
  LDB(bp, pixb[0], 8, 0) LDB(bq, pixb[0], 8, 1)
  LDB(br, pixb[0], 8, 2) LDB(bs, pixb[0], 8, 3)
  MF4(W1r, 0, bp) MF4(W1r, 1, bq) MF4(W1r, 2, br) MF4(W1r, 3, bs)
  EPI(h1b[0])
  __syncthreads();   // P1: h1(0) visible

  // ---- main pipeline: iter i = {L2(i), L3(i-1), stage(i+3), L1(i+1)} ----
  // STAGE placed after L3 so the stage is the NEWEST VMEM op (vmcnt FIFO).
#pragma unroll
  for (int i = 0; i <= 8; ++i) {
    if (i <= 7) {   // ===== L2(i): h1b[i&1] -> h2b[i&1], 3-deep rotation =====
      char* src = h1b[i & 1];
      INIT_ACC(bb2)
      LDB(bp, src, 9, 0)
      LDB(bq, src, 9, 1)
      LDB(br, src, 9, 2) MF4(W2r, 0, bp)
      LDB(bp, src, 9, 3) MF4(W2r, 1, bq)
      LDB(bq, src, 9, 4) MF4(W2r, 2, br)
      LDB(br, src, 9, 5) MF4(W2r, 3, bp)
      LDB(bp, src, 9, 6) MF4(W2r, 4, bq)
      LDB(bq, src, 9, 7) MF4(W2r, 5, br)
                         MF4(W2r, 6, bp)
                         MF4(W2r, 7, bq)
      EPI(h2b[i & 1])
    }

    if (i >= 1 && w < 2) {   // ===== L3(i-1): h2b[(i-1)&1] -> out (waves 0,1) =====
      const char* hs = h2b[(i - 1) & 1];
      const int m3 = (w << 4) + l15;
      f32x4 a3a = b3v;
      f32x4 a3b = {0.f, 0.f, 0.f, 0.f};
#pragma unroll
      for (int ks = 0; ks < 8; ks += 2) {
        bf16x8 bh0 = *reinterpret_cast<const bf16x8*>(
            hs + (((m3 << 9) + (ks << 6) + (kgrp << 1)) ^ ((l15 & 15) << 4)));
        bf16x8 bh1 = *reinterpret_cast<const bf16x8*>(
            hs + (((m3 << 9) + ((ks + 1) << 6) + (kgrp << 1)) ^ ((l15 & 15) << 4)));
        a3a = __builtin_amdgcn_mfma_f32_16x16x32_bf16(W3r[ks],     bh0, a3a, 0, 0, 0);
        a3b = __builtin_amdgcn_mfma_f32_16x16x32_bf16(W3r[ks + 1], bh1, a3b, 0, 0, 0);
      }
      if (lane < 16) {
        int pixel = pixbase + ((i - 1) << 5) + m3;
        int n = pixel >> 10, p = pixel & 1023;
        int ii = p >> 5, jj = p & 31;
        float* ob = out + ((size_t)((n << 5) + o) << 12) + (ii << 7) + (jj << 1);
        f32x2 r0 = { a3a[0] + a3b[0], a3a[1] + a3b[1] };
        f32x2 r1 = { a3a[2] + a3b[2], a3a[3] + a3b[3] };
        *reinterpret_cast<f32x2*>(ob) = r0;
        *reinterpret_cast<f32x2*>(ob + 64) = r1;
      }
    }

    if (i <= 4) STAGE(pixbase + ((i + 3) << 5), pixb[i % 3])   // tile i+3

    if (i <= 6) {   // ===== L1(i+1): pixb[(i+1)%3] -> h1b[(i+1)&1] =====
      char* psrc = pixb[(i + 1) % 3];
      INIT_ACC(bb1)
      LDB(bp, psrc, 8, 0) LDB(bq, psrc, 8, 1)
      LDB(br, psrc, 8, 2) LDB(bs, psrc, 8, 3)
      MF4(W1r, 0, bp) MF4(W1r, 1, bq) MF4(W1r, 2, br) MF4(W1r, 3, bs)
      EPI(h1b[(i + 1) & 1])
    }

    // barrier: float the newest stage (iters that issued one), else full drain.
    if (i <= 4) { PIPE_BARRIER(1) } else { PIPE_BARRIER(0) }
  }
}

extern "C" void kernel_launch(void* const* d_in, const int* in_sizes, int n_in,
                              void* d_out, int out_size, void* d_ws, size_t ws_size,
                              hipStream_t stream) {
  const float* x  = (const float*)d_in[0];
  const float* W1 = (const float*)d_in[1];
  const float* b1 = (const float*)d_in[2];
  const float* W2 = (const float*)d_in[3];
  const float* b2 = (const float*)d_in[4];
  const float* W3 = (const float*)d_in[5];
  const float* b3 = (const float*)d_in[6];
  float* out = (float*)d_out;

  char* ws = (char*)d_ws;
  unsigned short* pixw = (unsigned short*)(ws);
  unsigned short* W1t  = (unsigned short*)(ws + (size_t)(2u << 20));
  unsigned short* W2t  = (unsigned short*)(ws + (size_t)(4u << 20));
  unsigned short* W3t  = (unsigned short*)(ws + (size_t)(8u << 20));

  prepass_k<<<1536, 256, 0, stream>>>(x, pixw, W1, W1t, W2, W2t, W3, W3t);
  fused_mlp_k<<<1024, 512, 0, stream>>>(pixw, W1t, W2t, W3t, b1, b2, b3, out);
}